// Round 1
// 163.045 us; speedup vs baseline: 1.0065x; 1.0065x over previous
//
#include <hip/hip_runtime.h>

typedef __attribute__((ext_vector_type(8))) short short8;
typedef __attribute__((ext_vector_type(4))) short short4v;
typedef __attribute__((ext_vector_type(4))) float floatx4;
typedef __attribute__((ext_vector_type(2))) float floatx2;  // native vec: ok for NT builtins

// fp32 -> bf16 round-to-nearest-even (inputs finite)
static __device__ __forceinline__ unsigned short f2bf(float f) {
    union { float f; unsigned int u; } v; v.f = f;
    unsigned int u = v.u;
    return (unsigned short)((u + 0x7FFFu + ((u >> 16) & 1u)) >> 16);
}
static __device__ __forceinline__ float bf2f(short x) {
    return __uint_as_float(((unsigned int)(unsigned short)x) << 16);
}

// W1 [256,128] fp32 -> WT [256,128] bf16:
//   n' <  128: WT[n'][k] = W1[k][n']        (Y1 cols, k = top half)
//   n' >= 128: WT[n'][k] = W1[128+k][n'-128] (Y2 cols, k = bottom half)
__global__ void cvt_wt_kernel(const float* __restrict__ w1,
                              unsigned short* __restrict__ wt) {
    __shared__ unsigned short sT[32 * 130];
    const int b = blockIdx.x;            // 0..7 -> W1 k-rows [b*32, b*32+32)
    const int kg0 = b * 32;
    const int h = (kg0 >= 128) ? 1 : 0;
    const int kk0 = kg0 & 127;
    const int tid = threadIdx.x;
#pragma unroll
    for (int i = 0; i < 16; i++) {       // load 32x128, coalesced in n
        int idx = tid + i * 256;
        int k = idx >> 7, n = idx & 127;
        sT[k * 130 + n] = f2bf(w1[(kg0 + k) * 128 + n]);
    }
    __syncthreads();
#pragma unroll
    for (int i = 0; i < 16; i++) {       // store, coalesced in k
        int idx = tid + i * 256;
        int n = idx >> 5, k = idx & 31;
        wt[(h * 128 + n) * 128 + kk0 + k] = sT[k * 130 + n];
    }
}

// Phase 1 (r6-proven structure, unchanged compute): Y[n] = [x@W1_top + b1 | x@W1_bot],
// bf16. THIS ROUND'S single variable: Y goes to the WORKSPACE (x stays intact)
// when ws_size permits; falls back to the exact in-place form otherwise.
// Rationale: the in-place clobber of d_in[0] plausibly forces a timed ~51MB
// input restore per iteration (kernels sum to ~95µs vs dur_us 164µs).
// x/y deliberately NOT __restrict__: in the fallback they alias (same buffer);
// each lane reads only its own row, all loads precede all stores in program
// order, blocks own disjoint rows -> in-place safe, as before.
__global__ __launch_bounds__(512, 4) void node_gemm_kernel(
    const float* x,                            // in: X fp32 [N,128]
    unsigned short* y,                         // out: Y bf16 [N,256] (may alias x)
    const unsigned short* __restrict__ wt,     // [256,128] bf16 (pre-transposed)
    const float* __restrict__ b1, int N)
{
    __shared__ unsigned short sW[256 * 128];   // 64KB, slot-swizzled

    const int tid = threadIdx.x;
    const int lane = tid & 63, wave = tid >> 6;
    const int l15 = lane & 15, lq = lane >> 4;

    // Stage WT: 16B slot s of row r stored at slot s^(r&15).
#pragma unroll
    for (int i = 0; i < 8; i++) {
        int u = tid + i * 512;                 // 0..4095 16B-units
        int r = u >> 4, s = u & 15;
        *(short8*)&sW[r * 128 + ((s ^ r) & 15) * 8] =
            *(const short8*)&wt[r * 128 + s * 8];
    }
    __syncthreads();

    const int nr = blockIdx.x * 128 + wave * 16 + l15;
    const int nc = (nr < N) ? nr : (N - 1);
    const float* xrow = x + (size_t)nc * 128;

    floatx4 acc[16];
#pragma unroll
    for (int mt = 0; mt < 16; mt++) acc[mt] = (floatx4){0.f, 0.f, 0.f, 0.f};

#pragma unroll
    for (int kh = 0; kh < 2; kh++) {           // two k-halves of 64
        float4 xf[4];
#pragma unroll
        for (int q = 0; q < 4; q++)            // 4 loads in flight
            xf[q] = *(const float4*)(xrow + kh * 64 + (q >> 1) * 32 + lq * 8
                                     + (q & 1) * 4);
        short8 bf[2];
#pragma unroll
        for (int t = 0; t < 2; t++) {
            bf[t][0] = (short)f2bf(xf[2 * t].x);
            bf[t][1] = (short)f2bf(xf[2 * t].y);
            bf[t][2] = (short)f2bf(xf[2 * t].z);
            bf[t][3] = (short)f2bf(xf[2 * t].w);
            bf[t][4] = (short)f2bf(xf[2 * t + 1].x);
            bf[t][5] = (short)f2bf(xf[2 * t + 1].y);
            bf[t][6] = (short)f2bf(xf[2 * t + 1].z);
            bf[t][7] = (short)f2bf(xf[2 * t + 1].w);
        }
#pragma unroll
        for (int t = 0; t < 2; t++) {
            const int ks = kh * 2 + t;
#pragma unroll
            for (int mt = 0; mt < 16; mt++) {
                const short8 af = *(const short8*)
                    &sW[(mt * 16 + l15) * 128 + (((ks * 4 + lq) ^ l15) & 15) * 8];
                acc[mt] = __builtin_amdgcn_mfma_f32_16x16x32_bf16(af, bf[t],
                                                                  acc[mt], 0, 0, 0);
            }
        }
    }

    if (nr < N) {
        unsigned short* yrow = y + (size_t)nr * 256;
#pragma unroll
        for (int mt = 0; mt < 16; mt++) {
            const int oc = mt * 16 + lq * 4;   // out-col base (C row = lq*4+i)
            float4 bb = (mt < 8) ? *(const float4*)&b1[oc]
                                 : (float4){0.f, 0.f, 0.f, 0.f};
            short4v pk;
            pk[0] = (short)f2bf(acc[mt][0] + bb.x);
            pk[1] = (short)f2bf(acc[mt][1] + bb.y);
            pk[2] = (short)f2bf(acc[mt][2] + bb.z);
            pk[3] = (short)f2bf(acc[mt][3] + bb.w);
            *(short4v*)(yrow + oc) = pk;       // 8B store
        }
    }
}

// Phase 2: pure gather + reduce. out[e] = relu(Y1[s]+Y2[d]) @ W2 + b2.
// FROZEN at the measured per-CU demand ceiling (~6.7 TB/s at L1-miss level;
// r1-r6: every structure — occupancy 2x, barrier-free, double-buffer — lands
// at the same demand BW). 16 lanes/edge, 16-edge chunks double-buffered.
__global__ __launch_bounds__(256) void edge_kernel(
    const unsigned short* __restrict__ Y,      // [N,256] bf16 (rows 512B)
    const int* __restrict__ eidx,              // [2,E] int32
    const float* __restrict__ w2,              // [128,2]
    const float* __restrict__ b2,              // [2]
    float* __restrict__ out,                   // [E,2]
    int E, int n_nodes)
{
    const int tid = threadIdx.x;
    const int lane = tid & 63, wave = tid >> 6;
    const int r = lane >> 4, cl = lane & 15;

    float w20[8], w21[8];                      // W2 slice for ch c = cl*8 + j
#pragma unroll
    for (int q = 0; q < 4; q++) {
        const float4 f = *(const float4*)&w2[cl * 16 + q * 4];
        w20[q * 2]     = f.x; w21[q * 2]     = f.y;
        w20[q * 2 + 1] = f.z; w21[q * 2 + 1] = f.w;
    }
    const float bb0 = b2[0], bb1 = b2[1];

    const long eb = (long)blockIdx.x * 256 + wave * 64;
    const char* Yb = (const char*)Y;

    int sg[4], dg[4];
    short8 buf[2][2][4];                       // [phase][src/dst][group]

#define LOAD_IDX(CH)                                                        \
    _Pragma("unroll")                                                       \
    for (int g = 0; g < 4; g++) {                                           \
        long e = eb + (CH) * 16 + g * 4 + r; if (e >= E) e = E - 1;         \
        int s = __builtin_nontemporal_load(&eidx[e]);                       \
        int d = __builtin_nontemporal_load(&eidx[(long)E + e]);             \
        sg[g] = (s < 0) ? 0 : (s >= n_nodes ? n_nodes - 1 : s);             \
        dg[g] = (d < 0) ? 0 : (d >= n_nodes ? n_nodes - 1 : d);             \
    }
#define LOAD_Y(P)                                                           \
    _Pragma("unroll")                                                       \
    for (int g = 0; g < 4; g++) {                                           \
        buf[P][0][g] = *(const short8*)(Yb + (size_t)sg[g] * 512 + cl * 16);\
        buf[P][1][g] = *(const short8*)(Yb + (size_t)dg[g] * 512 + 256      \
                                        + cl * 16);                         \
    }

    LOAD_IDX(0); LOAD_Y(0);
    LOAD_IDX(1); LOAD_Y(1);

    for (int ch = 0; ch < 4; ch++) {
        const int p = ch & 1;
        if (ch < 2) { LOAD_IDX(ch + 2); }      // idx for the refill below
#pragma unroll
        for (int g = 0; g < 4; g++) {
            float p0 = 0.f, p1 = 0.f;
#pragma unroll
            for (int j = 0; j < 8; j++) {
                float f = bf2f(buf[p][0][g][j]) + bf2f(buf[p][1][g][j]);
                f = fmaxf(f, 0.f);             // b1 folded into Y1
                p0 = fmaf(f, w20[j], p0);
                p1 = fmaf(f, w21[j], p1);
            }
#pragma unroll
            for (int m = 1; m < 16; m <<= 1) { // reduce over 16 cl-lanes
                p0 += __shfl_xor(p0, m, 64);
                p1 += __shfl_xor(p1, m, 64);
            }
            if (cl == 0) {
                const long e = eb + ch * 16 + g * 4 + r;
                if (e < E) {
                    floatx2 o;
                    o.x = p0 + bb0; o.y = p1 + bb1;
                    __builtin_nontemporal_store(o, (floatx2*)&out[e * 2]);
                }
            }
        }
        if (ch < 2) { LOAD_Y(p); }             // refill freed buffer (chunk ch+2)
    }
#undef LOAD_IDX
#undef LOAD_Y
}

extern "C" void kernel_launch(void* const* d_in, const int* in_sizes, int n_in,
                              void* d_out, int out_size, void* d_ws, size_t ws_size,
                              hipStream_t stream) {
    float*       xy   = (float*)d_in[0];       // X fp32 [N,128]
    const int*   eidx = (const int*)d_in[1];
    const float* W1   = (const float*)d_in[2];
    const float* b1   = (const float*)d_in[3];
    const float* W2   = (const float*)d_in[4];
    const float* b2   = (const float*)d_in[5];
    float* out = (float*)d_out;

    const int n_node_elems = in_sizes[0];      // N*128
    const int N = n_node_elems / 128;
    const int E = in_sizes[1] / 2;

    unsigned short* wt = (unsigned short*)d_ws;  // 64KB at ws offset 0

    // Y placement: workspace if it fits (keeps d_in[0] pristine -> no timed
    // input-restore by the harness); else exact legacy in-place over X.
    const size_t y_off   = 1u << 18;           // 256KB (past wt, 512B-aligned)
    const size_t y_bytes = (size_t)N * 512;    // N rows x 256 bf16
    unsigned short* ybuf;
    if (ws_size >= y_off + y_bytes) {
        ybuf = (unsigned short*)((char*)d_ws + y_off);
    } else {
        ybuf = (unsigned short*)xy;            // fallback: in-place (aliases x)
    }

    cvt_wt_kernel<<<8, 256, 0, stream>>>(W1, wt);

    const int nblk1 = (N + 127) / 128;
    node_gemm_kernel<<<nblk1, 512, 0, stream>>>(xy, ybuf, wt, b1, N);

    const int nblk2 = (E + 255) / 256;
    edge_kernel<<<nblk2, 256, 0, stream>>>(ybuf, eidx, W2, b2, out, E, N);
}

// Round 2
// 157.679 us; speedup vs baseline: 1.0407x; 1.0340x over previous
//
#include <hip/hip_runtime.h>

typedef __attribute__((ext_vector_type(8))) short short8;
typedef __attribute__((ext_vector_type(4))) short short4v;
typedef __attribute__((ext_vector_type(4))) float floatx4;
typedef __attribute__((ext_vector_type(2))) float floatx2;  // native vec: ok for NT builtins

// fp32 -> bf16 round-to-nearest-even (inputs finite)
static __device__ __forceinline__ unsigned short f2bf(float f) {
    union { float f; unsigned int u; } v; v.f = f;
    unsigned int u = v.u;
    return (unsigned short)((u + 0x7FFFu + ((u >> 16) & 1u)) >> 16);
}
static __device__ __forceinline__ float bf2f(short x) {
    return __uint_as_float(((unsigned int)(unsigned short)x) << 16);
}

// W1 [256,128] fp32 -> WT [256,128] bf16:
//   n' <  128: WT[n'][k] = W1[k][n']        (Y1 cols, k = top half)
//   n' >= 128: WT[n'][k] = W1[128+k][n'-128] (Y2 cols, k = bottom half)
__global__ void cvt_wt_kernel(const float* __restrict__ w1,
                              unsigned short* __restrict__ wt) {
    __shared__ unsigned short sT[32 * 130];
    const int b = blockIdx.x;            // 0..7 -> W1 k-rows [b*32, b*32+32)
    const int kg0 = b * 32;
    const int h = (kg0 >= 128) ? 1 : 0;
    const int kk0 = kg0 & 127;
    const int tid = threadIdx.x;
#pragma unroll
    for (int i = 0; i < 16; i++) {       // load 32x128, coalesced in n
        int idx = tid + i * 256;
        int k = idx >> 7, n = idx & 127;
        sT[k * 130 + n] = f2bf(w1[(kg0 + k) * 128 + n]);
    }
    __syncthreads();
#pragma unroll
    for (int i = 0; i < 16; i++) {       // store, coalesced in k
        int idx = tid + i * 256;
        int n = idx >> 5, k = idx & 31;
        wt[(h * 128 + n) * 128 + kk0 + k] = sT[k * 130 + n];
    }
}

// Phase 1: Y[n] = [x@W1_top + b1 | x@W1_bot], bf16, Y in workspace (edge wins
// ~15µs from Y off d_in[0] — r1 measured). THIS ROUND's single variable:
// coalesced full-line Y stores via LDS-transpose epilogue. Rationale: with Y
// in a fresh region, the old 8B/lane scattered stores caused partial-line
// write-miss allocates in L2 (~51MB RMW fetch ≈ the +15µs gemm regression
// seen in r1). Epilogue reuses sW after a barrier; wave stores become
// lane-consecutive 16B (1KB/wave, full lines -> write-combine, no RMW).
__global__ __launch_bounds__(512, 4) void node_gemm_kernel(
    const float* x,                            // in: X fp32 [N,128]
    unsigned short* y,                         // out: Y bf16 [N,256]
    const unsigned short* __restrict__ wt,     // [256,128] bf16 (pre-transposed)
    const float* __restrict__ b1, int N)
{
    __shared__ unsigned short sW[256 * 128];   // 64KB, slot-swizzled

    const int tid = threadIdx.x;
    const int lane = tid & 63, wave = tid >> 6;
    const int l15 = lane & 15, lq = lane >> 4;

    // Stage WT: 16B slot s of row r stored at slot s^(r&15).
#pragma unroll
    for (int i = 0; i < 8; i++) {
        int u = tid + i * 512;                 // 0..4095 16B-units
        int r = u >> 4, s = u & 15;
        *(short8*)&sW[r * 128 + ((s ^ r) & 15) * 8] =
            *(const short8*)&wt[r * 128 + s * 8];
    }
    __syncthreads();

    const int nr = blockIdx.x * 128 + wave * 16 + l15;
    const int nc = (nr < N) ? nr : (N - 1);
    const float* xrow = x + (size_t)nc * 128;

    floatx4 acc[16];
#pragma unroll
    for (int mt = 0; mt < 16; mt++) acc[mt] = (floatx4){0.f, 0.f, 0.f, 0.f};

#pragma unroll
    for (int kh = 0; kh < 2; kh++) {           // two k-halves of 64
        float4 xf[4];
#pragma unroll
        for (int q = 0; q < 4; q++)            // 4 loads in flight
            xf[q] = *(const float4*)(xrow + kh * 64 + (q >> 1) * 32 + lq * 8
                                     + (q & 1) * 4);
        short8 bf[2];
#pragma unroll
        for (int t = 0; t < 2; t++) {
            bf[t][0] = (short)f2bf(xf[2 * t].x);
            bf[t][1] = (short)f2bf(xf[2 * t].y);
            bf[t][2] = (short)f2bf(xf[2 * t].z);
            bf[t][3] = (short)f2bf(xf[2 * t].w);
            bf[t][4] = (short)f2bf(xf[2 * t + 1].x);
            bf[t][5] = (short)f2bf(xf[2 * t + 1].y);
            bf[t][6] = (short)f2bf(xf[2 * t + 1].z);
            bf[t][7] = (short)f2bf(xf[2 * t + 1].w);
        }
#pragma unroll
        for (int t = 0; t < 2; t++) {
            const int ks = kh * 2 + t;
#pragma unroll
            for (int mt = 0; mt < 16; mt++) {
                const short8 af = *(const short8*)
                    &sW[(mt * 16 + l15) * 128 + (((ks * 4 + lq) ^ l15) & 15) * 8];
                acc[mt] = __builtin_amdgcn_mfma_f32_16x16x32_bf16(af, bf[t],
                                                                  acc[mt], 0, 0, 0);
            }
        }
    }

    // --- epilogue: LDS transpose for full-line coalesced Y stores ---
    __syncthreads();                           // all WT reads of sW complete
    {
        // write acc+bias into sW as Y-layout [128 rows][256 bf16], 16B slots
        // swizzled by row: logical slot s (0..31) stored at s ^ (row&15).
        const int lrow = wave * 16 + l15;      // local row 0..127
#pragma unroll
        for (int mt = 0; mt < 16; mt++) {
            const int oc = mt * 16 + lq * 4;   // out-col base within row
            float4 bb = (mt < 8) ? *(const float4*)&b1[oc]
                                 : (float4){0.f, 0.f, 0.f, 0.f};
            short4v pk;
            pk[0] = (short)f2bf(acc[mt][0] + bb.x);
            pk[1] = (short)f2bf(acc[mt][1] + bb.y);
            pk[2] = (short)f2bf(acc[mt][2] + bb.z);
            pk[3] = (short)f2bf(acc[mt][3] + bb.w);
            const int s = mt * 2 + (lq >> 1);  // 16B slot 0..31 (8B half: lq&1)
            *(short4v*)&sW[lrow * 256 + ((s ^ l15) * 8) + (lq & 1) * 4] = pk;
        }
    }
    __syncthreads();                           // block-wide transpose handoff
    {
        const int rbase = blockIdx.x * 128;
#pragma unroll
        for (int i = 0; i < 8; i++) {          // 512 thr x 8 x 16B = 64KB
            const int u = tid + i * 512;       // 16B unit 0..4095
            const int row = u >> 5, s = u & 31;
            const int grow = rbase + row;
            if (grow < N) {
                short8 v = *(const short8*)&sW[row * 256 + ((s ^ (row & 15)) * 8)];
                *(short8*)(y + (size_t)grow * 256 + s * 8) = v;  // lane-consecutive 16B
            }
        }
    }
}

// Phase 2: pure gather + reduce. out[e] = relu(Y1[s]+Y2[d]) @ W2 + b2.
// FROZEN at the measured per-CU demand ceiling (~6.7 TB/s at L1-miss level;
// every structure — occupancy 2x, barrier-free, double-buffer — lands at the
// same demand BW). 16 lanes/edge, 16-edge chunks double-buffered.
__global__ __launch_bounds__(256) void edge_kernel(
    const unsigned short* __restrict__ Y,      // [N,256] bf16 (rows 512B)
    const int* __restrict__ eidx,              // [2,E] int32
    const float* __restrict__ w2,              // [128,2]
    const float* __restrict__ b2,              // [2]
    float* __restrict__ out,                   // [E,2]
    int E, int n_nodes)
{
    const int tid = threadIdx.x;
    const int lane = tid & 63, wave = tid >> 6;
    const int r = lane >> 4, cl = lane & 15;

    float w20[8], w21[8];                      // W2 slice for ch c = cl*8 + j
#pragma unroll
    for (int q = 0; q < 4; q++) {
        const float4 f = *(const float4*)&w2[cl * 16 + q * 4];
        w20[q * 2]     = f.x; w21[q * 2]     = f.y;
        w20[q * 2 + 1] = f.z; w21[q * 2 + 1] = f.w;
    }
    const float bb0 = b2[0], bb1 = b2[1];

    const long eb = (long)blockIdx.x * 256 + wave * 64;
    const char* Yb = (const char*)Y;

    int sg[4], dg[4];
    short8 buf[2][2][4];                       // [phase][src/dst][group]

#define LOAD_IDX(CH)                                                        \
    _Pragma("unroll")                                                       \
    for (int g = 0; g < 4; g++) {                                           \
        long e = eb + (CH) * 16 + g * 4 + r; if (e >= E) e = E - 1;         \
        int s = __builtin_nontemporal_load(&eidx[e]);                       \
        int d = __builtin_nontemporal_load(&eidx[(long)E + e]);             \
        sg[g] = (s < 0) ? 0 : (s >= n_nodes ? n_nodes - 1 : s);             \
        dg[g] = (d < 0) ? 0 : (d >= n_nodes ? n_nodes - 1 : d);             \
    }
#define LOAD_Y(P)                                                           \
    _Pragma("unroll")                                                       \
    for (int g = 0; g < 4; g++) {                                           \
        buf[P][0][g] = *(const short8*)(Yb + (size_t)sg[g] * 512 + cl * 16);\
        buf[P][1][g] = *(const short8*)(Yb + (size_t)dg[g] * 512 + 256      \
                                        + cl * 16);                         \
    }

    LOAD_IDX(0); LOAD_Y(0);
    LOAD_IDX(1); LOAD_Y(1);

    for (int ch = 0; ch < 4; ch++) {
        const int p = ch & 1;
        if (ch < 2) { LOAD_IDX(ch + 2); }      // idx for the refill below
#pragma unroll
        for (int g = 0; g < 4; g++) {
            float p0 = 0.f, p1 = 0.f;
#pragma unroll
            for (int j = 0; j < 8; j++) {
                float f = bf2f(buf[p][0][g][j]) + bf2f(buf[p][1][g][j]);
                f = fmaxf(f, 0.f);             // b1 folded into Y1
                p0 = fmaf(f, w20[j], p0);
                p1 = fmaf(f, w21[j], p1);
            }
#pragma unroll
            for (int m = 1; m < 16; m <<= 1) { // reduce over 16 cl-lanes
                p0 += __shfl_xor(p0, m, 64);
                p1 += __shfl_xor(p1, m, 64);
            }
            if (cl == 0) {
                const long e = eb + ch * 16 + g * 4 + r;
                if (e < E) {
                    floatx2 o;
                    o.x = p0 + bb0; o.y = p1 + bb1;
                    __builtin_nontemporal_store(o, (floatx2*)&out[e * 2]);
                }
            }
        }
        if (ch < 2) { LOAD_Y(p); }             // refill freed buffer (chunk ch+2)
    }
#undef LOAD_IDX
#undef LOAD_Y
}

extern "C" void kernel_launch(void* const* d_in, const int* in_sizes, int n_in,
                              void* d_out, int out_size, void* d_ws, size_t ws_size,
                              hipStream_t stream) {
    float*       xy   = (float*)d_in[0];       // X fp32 [N,128]
    const int*   eidx = (const int*)d_in[1];
    const float* W1   = (const float*)d_in[2];
    const float* b1   = (const float*)d_in[3];
    const float* W2   = (const float*)d_in[4];
    const float* b2   = (const float*)d_in[5];
    float* out = (float*)d_out;

    const int n_node_elems = in_sizes[0];      // N*128
    const int N = n_node_elems / 128;
    const int E = in_sizes[1] / 2;

    unsigned short* wt = (unsigned short*)d_ws;  // 64KB at ws offset 0

    // Y placement: workspace if it fits (keeps d_in[0] pristine; edge gains
    // ~15µs — r1 measured); else legacy in-place over X.
    const size_t y_off   = 1u << 18;           // 256KB (past wt, 512B-aligned)
    const size_t y_bytes = (size_t)N * 512;    // N rows x 256 bf16
    unsigned short* ybuf;
    if (ws_size >= y_off + y_bytes) {
        ybuf = (unsigned short*)((char*)d_ws + y_off);
    } else {
        ybuf = (unsigned short*)xy;            // fallback: in-place (aliases x)
    }

    cvt_wt_kernel<<<8, 256, 0, stream>>>(W1, wt);

    const int nblk1 = (N + 127) / 128;
    node_gemm_kernel<<<nblk1, 512, 0, stream>>>(xy, ybuf, wt, b1, N);

    const int nblk2 = (E + 255) / 256;
    edge_kernel<<<nblk2, 256, 0, stream>>>(ybuf, eidx, W2, b2, out, E, N);
}